// Round 12
// baseline (1199.343 us; speedup 1.0000x reference)
//
#include <hip/hip_runtime.h>
#include <stdint.h>

#define NSTEPS 40
#define SBS 264   // LDS state-row stride in elements (256 + 8 pad; 528 B, 16B-aligned)

typedef float    floatx4  __attribute__((ext_vector_type(4)));
typedef __bf16   bf16x8   __attribute__((ext_vector_type(8)));
typedef __bf16   bf16x4   __attribute__((ext_vector_type(4)));
typedef uint32_t uint32x2 __attribute__((ext_vector_type(2)));

__device__ __forceinline__ __bf16 f2bf(float f){
  union { float f; uint32_t u; } v; v.f = f;
  uint32_t r = v.u + 0x7FFFu + ((v.u >> 16) & 1u);   // RNE (prep kernels only)
  union { uint16_t s; __bf16 b; } o; o.s = (uint16_t)(r >> 16);
  return o.b;
}
__device__ __forceinline__ float bf2f(__bf16 b){
  union { uint16_t s; __bf16 b; } i; i.b = b;
  union { uint32_t u; float f; } o; o.u = ((uint32_t)i.s) << 16;
  return o.f;
}
__device__ __forceinline__ uint32_t cvt_pk_bf16(float lo, float hi){
  uint32_t d;
  asm("v_cvt_pk_bf16_f32 %0, %1, %2" : "=v"(d) : "v"(lo), "v"(hi));
  return d;
}
__device__ __forceinline__ float fast_tanh(float x){
  float e = __expf(2.0f * x);
  return __builtin_fmaf(-2.0f, __builtin_amdgcn_rcpf(e + 1.0f), 1.0f);
}

// ---- prep1: bf16-cast + transpose weights; beta = b2 @ W1 (fp32) ----
__global__ void prep_kernel(const float* __restrict__ Ws,
                            const float* __restrict__ W1,
                            const float* __restrict__ W2,
                            const float* __restrict__ b2,
                            __bf16* __restrict__ WsT,
                            __bf16* __restrict__ W1T,
                            __bf16* __restrict__ W2T,
                            float* __restrict__ beta){
  int tid = blockIdx.x * blockDim.x + threadIdx.x;
  int stride = gridDim.x * blockDim.x;
  for (int i = tid; i < 512*256; i += stride){
    int k = i >> 8, n = i & 255;
    WsT[n*512 + k] = f2bf(Ws[i]);
  }
  for (int i = tid; i < 256*256; i += stride){
    int k = i >> 8, n = i & 255;
    W1T[n*256 + k] = f2bf(W1[i]);
    W2T[n*256 + k] = f2bf(W2[i]);
  }
  if (blockIdx.x == 0){
    int j = threadIdx.x;            // 256 threads
    float acc = 0.f;
    for (int l = 0; l < 256; ++l)
      acc = __builtin_fmaf(b2[l], W1[l*256 + j], acc);
    beta[j] = acc;
  }
}

// ---- prep2: MT[j][i] = (W2@W1)[i][j] (fp32 dot, bf16 store) ----
__global__ void prep_mt(const float* __restrict__ W1,
                        const float* __restrict__ W2,
                        __bf16* __restrict__ MT){
  __shared__ float w2row[256];
  const int i = blockIdx.x;
  const int j = threadIdx.x;
  w2row[j] = W2[i*256 + j];
  __syncthreads();
  float acc = 0.f;
  for (int l = 0; l < 256; ++l)
    acc = __builtin_fmaf(w2row[l], W1[l*256 + j], acc);
  MT[j*256 + i] = f2bf(acc);
}

// Fused ODE kernel, round 12: y-space recursion + IN-SLOT SOFTWARE PIPELINE.
// r11 counters showed MFMA(28%)+VALU(51%)+LDS phases SUM (8490 cyc/slot =
// 2360+4295+~1800): barrier-lockstep waves have no cross-phase overlap. nt
// tiles are independent, so each slot is restructured as
//   GEMM(0); GEMM(1)|POST(0); GEMM(2)|POST(1); GEMM(3)|POST(2); POST(3)
// (POST = bookkeeping+tanh+write for one nt) -- VALU of POST(n-1) fills the
// MFMA shadow of GEMM(n) in-wave, inside the same barrier interval. Slot body
// specialized per e (constant-folded) to keep one big schedulable block;
// accumulators k-split into 2x4-deep MFMA chains for latency.
__global__ __launch_bounds__(512, 2)
void ode_kernel(const float* __restrict__ x,
                const float* __restrict__ b_state,
                const float* __restrict__ W1full,   // 257x256 fp32 (row 256 = t row)
                const float* __restrict__ b1,
                const float* __restrict__ b2,
                const float* __restrict__ Wout,     // 256x18 fp32
                const float* __restrict__ bout,
                const __bf16* __restrict__ WsT,     // [256][512]
                const __bf16* __restrict__ W1Tg,    // [256][256]
                const __bf16* __restrict__ W2Tg,    // [256][256]
                const __bf16* __restrict__ MTg,     // [256][256]
                const float* __restrict__ betag,    // [256]
                float* __restrict__ out)
{
  __shared__ __align__(16) __bf16 lds_sb0[64*SBS];   // 33 KB  z double-buffer A
  __shared__ __align__(16) __bf16 lds_sb1[64*SBS];   // 33 KB  z double-buffer B
  __shared__ __align__(16) __bf16 lds_h0[64*SBS];    // 33 KB  h0 (kept to epilogue)
  __shared__ __align__(16) float  lds_bias[4*256];   //  4 KB  b1 | wt | b2 | beta

  const int tid  = threadIdx.x;
  const int wave = tid >> 6;       // 0..7
  const int lane = tid & 63;
  const int c16  = lane & 15;
  const int q    = lane >> 4;      // 0..3
  const int nh0  = wave * 32;      // this wave's y-row base (32 rows)
  const int m0   = blockIdx.x * 64;

  if (tid < 256){
    lds_bias[tid]       = b1[tid];
    lds_bias[256 + tid] = W1full[256*256 + tid];  // time row of W_dyn1
    lds_bias[512 + tid] = b2[tid];
    lds_bias[768 + tid] = betag[tid];
  }

  // ---- addressing (padded-linear) ----
  int arow[2];
  #pragma unroll
  for (int mt = 0; mt < 2; ++mt) arow[mt] = nh0 + mt*16 + c16;
  const int browc = c16 * SBS;      // B batch-row base (nt adds 16*SBS)
  const int n04   = nh0 + 4*q;      // C/D row base (mt adds 16)
  const int bidx  = n04;

  // ---- resident M fragments (A-operand), 64 regs ----
  bf16x8 Mf[2][8];
  #pragma unroll
  for (int mt = 0; mt < 2; ++mt)
    #pragma unroll
    for (int kt = 0; kt < 8; ++kt)
      Mf[mt][kt] = *(const bf16x8*)&MTg[arow[mt]*256 + kt*32 + q*8];
  #pragma unroll
  for (int mt = 0; mt < 2; ++mt)
    #pragma unroll
    for (int kt = 0; kt < 8; ++kt)
      asm volatile("" : "+v"(Mf[mt][kt]));

  floatx4 y[2][4], p[2][4], sM[2][4], w[2][4];
  const floatx4 vzero = {0.f, 0.f, 0.f, 0.f};
  #pragma unroll
  for (int mt = 0; mt < 2; ++mt)
    #pragma unroll
    for (int nt = 0; nt < 4; ++nt){ sM[mt][nt] = vzero; }

  // ---- phase 0: h0 = tanh(x@Ws + bs) -> lds_h0 ----
  {
    #pragma unroll
    for (int mt = 0; mt < 2; ++mt){
      floatx4 bsv;
      #pragma unroll
      for (int r = 0; r < 4; ++r) bsv[r] = b_state[nh0 + mt*16 + 4*q + r];
      #pragma unroll
      for (int nt = 0; nt < 4; ++nt) p[mt][nt] = bsv;
    }
    #pragma unroll 1
    for (int kt = 0; kt < 16; ++kt){
      bf16x8 b[4];
      #pragma unroll
      for (int nt = 0; nt < 4; ++nt){
        const float* px = &x[(size_t)(m0 + nt*16 + c16)*512 + kt*32 + q*8];
        floatx4 f0 = *(const floatx4*)px;
        floatx4 f1 = *(const floatx4*)(px + 4);
        union { uint32_t u[4]; bf16x8 v; } pk;
        pk.u[0] = cvt_pk_bf16(f0[0], f0[1]);
        pk.u[1] = cvt_pk_bf16(f0[2], f0[3]);
        pk.u[2] = cvt_pk_bf16(f1[0], f1[1]);
        pk.u[3] = cvt_pk_bf16(f1[2], f1[3]);
        b[nt] = pk.v;
      }
      #pragma unroll
      for (int mt = 0; mt < 2; ++mt){
        bf16x8 a = *(const bf16x8*)&WsT[arow[mt]*512 + kt*32 + q*8];
        #pragma unroll
        for (int nt = 0; nt < 4; ++nt)
          p[mt][nt] = __builtin_amdgcn_mfma_f32_16x16x32_bf16(a, b[nt], p[mt][nt], 0, 0, 0);
      }
    }
    #pragma unroll
    for (int mt = 0; mt < 2; ++mt)
      #pragma unroll
      for (int nt = 0; nt < 4; ++nt){
        float v0 = fast_tanh(p[mt][nt][0]);
        float v1 = fast_tanh(p[mt][nt][1]);
        float v2 = fast_tanh(p[mt][nt][2]);
        float v3 = fast_tanh(p[mt][nt][3]);
        uint32x2 wv = { cvt_pk_bf16(v0, v1), cvt_pk_bf16(v2, v3) };
        *(uint32x2*)&lds_h0[browc + nt*(16*SBS) + n04 + mt*16] = wv;
      }
  }
  __syncthreads();

  // ---- y0 = h0 @ W1 (transposed), W1 frags transient ----
  {
    bf16x8 W1f[2][8];
    #pragma unroll
    for (int mt = 0; mt < 2; ++mt)
      #pragma unroll
      for (int kt = 0; kt < 8; ++kt)
        W1f[mt][kt] = *(const bf16x8*)&W1Tg[arow[mt]*256 + kt*32 + q*8];
    #pragma unroll
    for (int mt = 0; mt < 2; ++mt)
      #pragma unroll
      for (int nt = 0; nt < 4; ++nt) y[mt][nt] = vzero;
    #pragma unroll
    for (int kt = 0; kt < 8; ++kt){
      bf16x8 b[4];
      #pragma unroll
      for (int nt = 0; nt < 4; ++nt)
        b[nt] = *(const bf16x8*)&lds_h0[browc + nt*(16*SBS) + kt*32 + q*8];
      #pragma unroll
      for (int mt = 0; mt < 2; ++mt)
        #pragma unroll
        for (int nt = 0; nt < 4; ++nt)
          y[mt][nt] = __builtin_amdgcn_mfma_f32_16x16x32_bf16(W1f[mt][kt], b[nt], y[mt][nt], 0, 0, 0);
    }
  }

  const float dt  = 1.0f / NSTEPS;
  const float hdt = 0.5f * dt;
  const float dt6 = dt / 6.0f;

  // ---- slot 0: z0 = tanh(y + b1) (t=0), w = z0 -> SB0 ----
  #pragma unroll
  for (int mt = 0; mt < 2; ++mt){
    floatx4 b1v = *(const floatx4*)&lds_bias[bidx + mt*16];
    #pragma unroll
    for (int nt = 0; nt < 4; ++nt){
      floatx4 zv;
      #pragma unroll
      for (int r = 0; r < 4; ++r) zv[r] = fast_tanh(y[mt][nt][r] + b1v[r]);
      w[mt][nt] = zv;
      uint32x2 wv = { cvt_pk_bf16(zv[0], zv[1]), cvt_pk_bf16(zv[2], zv[3]) };
      *(uint32x2*)&lds_sb0[browc + nt*(16*SBS) + n04 + mt*16] = wv;
    }
  }
  __syncthreads();

  // ---- pipelined slot macros ----
  // GEMM_NT: p[.][NT] = beta + z@M for batch tile NT (k-split 2x4 chains)
#define GEMM_NT(NT) { \
    bf16x8 bfr[8]; \
    _Pragma("unroll") \
    for (int kt = 0; kt < 8; ++kt) \
      bfr[kt] = *(const bf16x8*)&sbR[browc + (NT)*(16*SBS) + kt*32 + q*8]; \
    floatx4 c0[2], c1[2]; \
    _Pragma("unroll") \
    for (int mt = 0; mt < 2; ++mt){ c0[mt] = bev[mt]; c1[mt] = vzero; } \
    _Pragma("unroll") \
    for (int kt = 0; kt < 4; ++kt) \
      _Pragma("unroll") \
      for (int mt = 0; mt < 2; ++mt){ \
        c0[mt] = __builtin_amdgcn_mfma_f32_16x16x32_bf16(Mf[mt][kt],   bfr[kt],   c0[mt], 0, 0, 0); \
        c1[mt] = __builtin_amdgcn_mfma_f32_16x16x32_bf16(Mf[mt][kt+4], bfr[kt+4], c1[mt], 0, 0, 0); \
      } \
    _Pragma("unroll") \
    for (int mt = 0; mt < 2; ++mt) p[mt][NT] = c0[mt] + c1[mt]; \
  }

  // POST_NT: bookkeeping + tanh + write for batch tile NT. EC constant-folds.
#define POST_NT(NT, EC, CIN, WZ) { \
    _Pragma("unroll") \
    for (int mt = 0; mt < 2; ++mt){ \
      floatx4 pv = p[mt][NT]; \
      if ((EC) == 0){ \
        _Pragma("unroll") \
        for (int r = 0; r < 4; ++r) \
          y[mt][NT][r] = __builtin_fmaf(dt6, sM[mt][NT][r] + pv[r], y[mt][NT][r]); \
      } else if ((EC) == 1){ \
        sM[mt][NT] = pv; \
      } else { \
        _Pragma("unroll") \
        for (int r = 0; r < 4; ++r) \
          sM[mt][NT][r] = __builtin_fmaf(2.0f, pv[r], sM[mt][NT][r]); \
      } \
      floatx4 zv; \
      _Pragma("unroll") \
      for (int r = 0; r < 4; ++r){ \
        float ye = __builtin_fmaf((CIN), pv[r], y[mt][NT][r]); \
        zv[r] = fast_tanh(ye + bias[mt][r]); \
        w[mt][NT][r] = __builtin_fmaf((WZ), zv[r], w[mt][NT][r]); \
      } \
      uint32x2 wv = { cvt_pk_bf16(zv[0], zv[1]), cvt_pk_bf16(zv[2], zv[3]) }; \
      *(uint32x2*)&sbW[browc + (NT)*(16*SBS) + n04 + mt*16] = wv; \
    } \
  }

#define SLOT(EC, CIN, WZ) { \
    GEMM_NT(0) \
    GEMM_NT(1) POST_NT(0, EC, CIN, WZ) \
    GEMM_NT(2) POST_NT(1, EC, CIN, WZ) \
    GEMM_NT(3) POST_NT(2, EC, CIN, WZ) \
    POST_NT(3, EC, CIN, WZ) \
  }

  // ---- main loop: slots i = 1..159, ONE GEMM + ONE barrier each ----
  #pragma unroll 1
  for (int i = 1; i < NSTEPS*4; ++i){
    const int e = i & 3;
    const float cin = (e == 0) ? 0.0f : ((e == 3) ? dt : hdt);
    const float te  = dt * (float)(i >> 2) + cin;
    const __bf16* sbR = ((i & 1) == 1) ? lds_sb0 : lds_sb1;
    __bf16*       sbW = ((i & 1) == 1) ? lds_sb1 : lds_sb0;

    floatx4 bias[2], bev[2];
    #pragma unroll
    for (int mt = 0; mt < 2; ++mt){
      floatx4 b1v = *(const floatx4*)&lds_bias[bidx + mt*16];
      floatx4 wtv = *(const floatx4*)&lds_bias[256 + bidx + mt*16];
      #pragma unroll
      for (int r = 0; r < 4; ++r) bias[mt][r] = __builtin_fmaf(te, wtv[r], b1v[r]);
      bev[mt] = *(const floatx4*)&lds_bias[768 + bidx + mt*16];
    }

    if (e == 0)      SLOT(0, 0.0f, 1.0f)
    else if (e == 1) SLOT(1, hdt,  2.0f)
    else if (e == 2) SLOT(2, hdt,  2.0f)
    else             SLOT(3, dt,   1.0f)

    __syncthreads();
  }

  // ---- epilogue: h_T = h0 + (dt6*w) @ W2 + b2, then out = h_T @ Wout ----
  #pragma unroll
  for (int mt = 0; mt < 2; ++mt)
    #pragma unroll
    for (int nt = 0; nt < 4; ++nt){
      float v0 = dt6 * w[mt][nt][0];
      float v1 = dt6 * w[mt][nt][1];
      float v2 = dt6 * w[mt][nt][2];
      float v3 = dt6 * w[mt][nt][3];
      uint32x2 wv = { cvt_pk_bf16(v0, v1), cvt_pk_bf16(v2, v3) };
      *(uint32x2*)&lds_sb0[browc + nt*(16*SBS) + n04 + mt*16] = wv;
    }
  __syncthreads();
  {
    bf16x8 W2f[2][8];
    #pragma unroll
    for (int mt = 0; mt < 2; ++mt)
      #pragma unroll
      for (int kt = 0; kt < 8; ++kt)
        W2f[mt][kt] = *(const bf16x8*)&W2Tg[arow[mt]*256 + kt*32 + q*8];
    floatx4 hF[2][4];
    #pragma unroll
    for (int mt = 0; mt < 2; ++mt){
      floatx4 b2v = *(const floatx4*)&lds_bias[512 + bidx + mt*16];
      #pragma unroll
      for (int nt = 0; nt < 4; ++nt) hF[mt][nt] = b2v;
    }
    #pragma unroll
    for (int kt = 0; kt < 8; ++kt){
      bf16x8 b[4];
      #pragma unroll
      for (int nt = 0; nt < 4; ++nt)
        b[nt] = *(const bf16x8*)&lds_sb0[browc + nt*(16*SBS) + kt*32 + q*8];
      #pragma unroll
      for (int mt = 0; mt < 2; ++mt)
        #pragma unroll
        for (int nt = 0; nt < 4; ++nt)
          hF[mt][nt] = __builtin_amdgcn_mfma_f32_16x16x32_bf16(W2f[mt][kt], b[nt], hF[mt][nt], 0, 0, 0);
    }
    #pragma unroll
    for (int mt = 0; mt < 2; ++mt)
      #pragma unroll
      for (int nt = 0; nt < 4; ++nt){
        bf16x4 h0v = *(const bf16x4*)&lds_h0[browc + nt*(16*SBS) + n04 + mt*16];
        #pragma unroll
        for (int r = 0; r < 4; ++r) hF[mt][nt][r] += bf2f(h0v[r]);
        uint32x2 wv = { cvt_pk_bf16(hF[mt][nt][0], hF[mt][nt][1]),
                        cvt_pk_bf16(hF[mt][nt][2], hF[mt][nt][3]) };
        *(uint32x2*)&lds_sb1[browc + nt*(16*SBS) + n04 + mt*16] = wv;
      }
  }
  __syncthreads();
  {
    const int r  = tid & 63;         // batch row within block
    const int og = tid >> 6;         // 8 groups; first 6 cover 18 outputs
    if (og < 6){
      const int obase = og * 3;
      float acc[3] = {0.f, 0.f, 0.f};
      for (int c = 0; c < 32; ++c){
        bf16x8 h8 = *(const bf16x8*)&lds_sb1[r*SBS + c*8];
        #pragma unroll
        for (int j = 0; j < 8; ++j){
          float hval = bf2f(h8[j]);
          int kk = c*8 + j;
          #pragma unroll
          for (int oo = 0; oo < 3; ++oo)
            acc[oo] += hval * Wout[kk*18 + obase + oo];
        }
      }
      #pragma unroll
      for (int oo = 0; oo < 3; ++oo)
        out[(size_t)(m0 + r)*18 + obase + oo] = acc[oo] + bout[obase + oo];
    }
  }
}

extern "C" void kernel_launch(void* const* d_in, const int* in_sizes, int n_in,
                              void* d_out, int out_size, void* d_ws, size_t ws_size,
                              hipStream_t stream){
  const float* x   = (const float*)d_in[0];
  const float* Ws  = (const float*)d_in[1];
  const float* bs  = (const float*)d_in[2];
  const float* W1  = (const float*)d_in[3];
  const float* b1  = (const float*)d_in[4];
  const float* W2  = (const float*)d_in[5];
  const float* b2  = (const float*)d_in[6];
  const float* Wo  = (const float*)d_in[7];
  const float* bo  = (const float*)d_in[8];
  float* out = (float*)d_out;

  __bf16* WsT  = (__bf16*)d_ws;          // 256x512 bf16 = 256 KB
  __bf16* W1T  = WsT + 512*256;          // 256x256 bf16 = 128 KB
  __bf16* W2T  = W1T + 256*256;          // 256x256 bf16 = 128 KB
  __bf16* MT   = W2T + 256*256;          // 256x256 bf16 = 128 KB
  float*  beta = (float*)(MT + 256*256); // 256 fp32 = 1 KB

  prep_kernel<<<128, 256, 0, stream>>>(Ws, W1, W2, b2, WsT, W1T, W2T, beta);
  prep_mt<<<256, 256, 0, stream>>>(W1, W2, MT);
  ode_kernel<<<256, 512, 0, stream>>>(x, bs, W1, b1, b2, Wo, bo,
                                      WsT, W1T, W2T, MT, beta, out);
}